// Round 1
// baseline (955.458 us; speedup 1.0000x reference)
//
#include <hip/hip_runtime.h>
#include <hip/hip_bf16.h>

// Problem constants
#define HDIM 64
#define WDIM 64
#define NPOS 4096          // 64*64
#define CD   64            // channel dim
#define NB   4             // batch

typedef __bf16 bf16x8_t __attribute__((ext_vector_type(8)));
typedef float  f32x4_t  __attribute__((ext_vector_type(4)));

static __device__ __forceinline__ unsigned short f2bf(float f) {
    return __builtin_bit_cast(unsigned short, __float2bfloat16(f));
}

// ---------------------------------------------------------------------------
// Direct 3x3 conv + folded BN + ReLU.
//  in: fp32 NCHW (in0 = first 64 ci, in1 = ci 64..127 when cin==128)
//  layout 0: out bf16 [b][n][co]   (position-major, for Q/K)
//  layout 1: out bf16 [b][co][n]   (channel-major, for V)
//  layout 2: out fp32 [b][co][n]   (NCHW, final output)
// grid: (128 = h*2 halves, NB). block 256. Each block: one h row, 32 couts.
// thread t: w = t&63, cog = t>>6 (0..3) -> co = half*32 + cog*8 + cc (cc<8)
// ---------------------------------------------------------------------------
__global__ __launch_bounds__(256) void conv3x3_kernel(
    const float* __restrict__ in0, const float* __restrict__ in1,
    const float* __restrict__ wgt, const float* __restrict__ scale,
    const float* __restrict__ shift, void* __restrict__ out,
    int cin, int layout)
{
    __shared__ float smem[64 * 3 * 66];   // [ci_chunk 64][3 rows][66 cols]
    const int h    = blockIdx.x >> 1;
    const int half = blockIdx.x & 1;
    const int b    = blockIdx.y;
    const int t    = threadIdx.x;
    const int w    = t & 63;
    const int cog  = t >> 6;
    const int co0  = half * 32 + cog * 8;

    float acc[8];
#pragma unroll
    for (int i = 0; i < 8; ++i) acc[i] = 0.f;

    for (int cc0 = 0; cc0 < cin; cc0 += 64) {
        __syncthreads();   // protect smem reuse across chunks
        for (int idx = t; idx < 64 * 3 * 66; idx += 256) {
            const int cil = idx / 198;
            const int rem = idx - cil * 198;
            const int r   = rem / 66;
            const int wc  = rem - r * 66 - 1;   // input col
            const int hh  = h - 1 + r;          // input row
            const int ci  = cc0 + cil;
            float v = 0.f;
            if (hh >= 0 && hh < 64 && wc >= 0 && wc < 64) {
                const float* src = (ci < 64) ? in0 : in1;
                const int cm = ci & 63;
                v = src[(((size_t)b * 64 + cm) * 64 + hh) * 64 + wc];
            }
            smem[idx] = v;
        }
        __syncthreads();

        for (int cil = 0; cil < 64; ++cil) {
            const int ci = cc0 + cil;
            const float* row = &smem[cil * 198];
            const float a00 = row[w],       a01 = row[w + 1],       a02 = row[w + 2];
            const float a10 = row[66 + w],  a11 = row[66 + w + 1],  a12 = row[66 + w + 2];
            const float a20 = row[132 + w], a21 = row[132 + w + 1], a22 = row[132 + w + 2];
            const float* wp = wgt + ((size_t)co0 * cin + ci) * 9;
#pragma unroll
            for (int cc = 0; cc < 8; ++cc) {
                const float* q = wp + (size_t)cc * cin * 9;
                float s0 = fmaf(a00, q[0], fmaf(a01, q[1], a02 * q[2]));
                float s1 = fmaf(a10, q[3], fmaf(a11, q[4], a12 * q[5]));
                float s2 = fmaf(a20, q[6], fmaf(a21, q[7], a22 * q[8]));
                acc[cc] += s0 + s1 + s2;
            }
        }
    }

    const int n = h * 64 + w;
    if (layout == 0) {
        union { unsigned short us[8]; uint4 u; } pk;
#pragma unroll
        for (int cc = 0; cc < 8; ++cc) {
            const int co = co0 + cc;
            float v = fmaxf(fmaf(acc[cc], scale[co], shift[co]), 0.f);
            pk.us[cc] = f2bf(v);
        }
        unsigned short* o = (unsigned short*)out + ((size_t)b * NPOS + n) * CD + co0;
        *(uint4*)o = pk.u;
    } else if (layout == 1) {
#pragma unroll
        for (int cc = 0; cc < 8; ++cc) {
            const int co = co0 + cc;
            float v = fmaxf(fmaf(acc[cc], scale[co], shift[co]), 0.f);
            ((unsigned short*)out)[((size_t)b * CD + co) * NPOS + n] = f2bf(v);
        }
    } else {
#pragma unroll
        for (int cc = 0; cc < 8; ++cc) {
            const int co = co0 + cc;
            float v = fmaxf(fmaf(acc[cc], scale[co], shift[co]), 0.f);
            ((float*)out)[((size_t)b * CD + co) * NPOS + n] = v;
        }
    }
}

// ---------------------------------------------------------------------------
// Flash attention:  out[c,m] = sum_n softmax_n( Kt[m,:]·Qt[n,:] ) * V[c,n]
//   Qt/Kt: bf16 [b][pos][64]   V: bf16 [b][64][pos]
//   refine = gamma * att + resid, written fp32 [b][c][n]
// grid: (4096/64 m-blocks, NB, 2 attends). block 256 = 4 waves, 16 m rows/wave.
// Per wave, per 64-n tile:
//   St (S transposed) via mfma(A=Qt-frag, B=Kt-frag): lane holds S[m=l&15][4g+r]
//   online softmax per lane (all 16 values share one m; reduce across g via
//   shfl_xor 16/32), P -> per-wave LDS tile [16][68] bf16, PV via
//   mfma(A=V-frag, B=P-frag) accumulating O[c=4g+r][m=l&15].
// ---------------------------------------------------------------------------
__global__ __launch_bounds__(256) void attn_kernel(
    const unsigned short* __restrict__ Qt,
    const unsigned short* __restrict__ KtR, const unsigned short* __restrict__ KtI,
    const unsigned short* __restrict__ VR,  const unsigned short* __restrict__ VI,
    const float* __restrict__ x, const float* __restrict__ y,
    const float* __restrict__ g1, const float* __restrict__ g2,
    float* __restrict__ refR, float* __restrict__ refI)
{
    const int b    = blockIdx.y;
    const int att  = blockIdx.z;
    const int lane = threadIdx.x & 63;
    const int wv   = threadIdx.x >> 6;
    const int l15  = lane & 15;
    const int g    = lane >> 4;
    const int m0   = blockIdx.x * 64 + wv * 16;

    const unsigned short* Kt = att ? KtI : KtR;
    const unsigned short* V  = att ? VI  : VR;
    const float* resid       = att ? x   : y;     // inf uses +x, rgb uses +y
    const float gamma        = att ? g2[0] : g1[0];
    float* outp              = att ? refI : refR;

    const unsigned short* Qb = Qt + (size_t)b * NPOS * CD;
    const unsigned short* Kb = Kt + (size_t)b * NPOS * CD;
    const unsigned short* Vb = V  + (size_t)b * CD * NPOS;

    // K fragments for this wave's 16 m rows (B operand: col=m=l15, k=d)
    const bf16x8_t bK0 = *(const bf16x8_t*)&Kb[(size_t)(m0 + l15) * CD + g * 8];
    const bf16x8_t bK1 = *(const bf16x8_t*)&Kb[(size_t)(m0 + l15) * CD + 32 + g * 8];

    __shared__ unsigned short plds[4][16 * 68];   // per-wave P tile, pad to 68
    unsigned short* pl = plds[wv];

    f32x4_t O[4];
#pragma unroll
    for (int i = 0; i < 4; ++i) O[i] = (f32x4_t){0.f, 0.f, 0.f, 0.f};
    float mrun = -3.0e38f, lsum = 0.f;

    for (int n0 = 0; n0 < NPOS; n0 += 64) {
        // ---- QK^T (transposed: D[row=n, col=m]) ----
        f32x4_t St[4];
#pragma unroll
        for (int nt = 0; nt < 4; ++nt) {
            const unsigned short* qp = &Qb[(size_t)(n0 + nt * 16 + l15) * CD + g * 8];
            bf16x8_t a0 = *(const bf16x8_t*)qp;
            bf16x8_t a1 = *(const bf16x8_t*)(qp + 32);
            f32x4_t c = (f32x4_t){0.f, 0.f, 0.f, 0.f};
            c = __builtin_amdgcn_mfma_f32_16x16x32_bf16(a0, bK0, c, 0, 0, 0);
            c = __builtin_amdgcn_mfma_f32_16x16x32_bf16(a1, bK1, c, 0, 0, 0);
            St[nt] = c;
        }
        // ---- online softmax (each lane's 16 values share m = m0+l15) ----
        float tmax = St[0][0];
#pragma unroll
        for (int nt = 0; nt < 4; ++nt)
#pragma unroll
            for (int r = 0; r < 4; ++r) tmax = fmaxf(tmax, St[nt][r]);
        tmax = fmaxf(tmax, __shfl_xor(tmax, 16));
        tmax = fmaxf(tmax, __shfl_xor(tmax, 32));
        const float mnew = fmaxf(mrun, tmax);
        const float corr = __expf(mrun - mnew);
        float psum = 0.f;
        unsigned int pw[8];
#pragma unroll
        for (int nt = 0; nt < 4; ++nt) {
            float p0 = __expf(St[nt][0] - mnew);
            float p1 = __expf(St[nt][1] - mnew);
            float p2 = __expf(St[nt][2] - mnew);
            float p3 = __expf(St[nt][3] - mnew);
            psum += (p0 + p1) + (p2 + p3);
            pw[nt * 2 + 0] = (unsigned)f2bf(p0) | ((unsigned)f2bf(p1) << 16);
            pw[nt * 2 + 1] = (unsigned)f2bf(p2) | ((unsigned)f2bf(p3) << 16);
        }
        psum += __shfl_xor(psum, 16);
        psum += __shfl_xor(psum, 32);
        lsum = lsum * corr + psum;
        mrun = mnew;
#pragma unroll
        for (int i = 0; i < 4; ++i) {
            O[i][0] *= corr; O[i][1] *= corr; O[i][2] *= corr; O[i][3] *= corr;
        }
        // ---- P -> LDS (per-wave region, no barrier needed) ----
#pragma unroll
        for (int nt = 0; nt < 4; ++nt) {
            *(uint2*)&pl[l15 * 68 + nt * 16 + g * 4] =
                make_uint2(pw[nt * 2], pw[nt * 2 + 1]);
        }
        // ---- PV: O[c,m] += V[c,n-chunk] * P[m,n-chunk] ----
#pragma unroll
        for (int nc = 0; nc < 2; ++nc) {
            union { bf16x8_t v; uint2 d2[2]; } bp;
            bp.d2[0] = *(uint2*)&pl[l15 * 68 + nc * 32 + g * 8];
            bp.d2[1] = *(uint2*)&pl[l15 * 68 + nc * 32 + g * 8 + 4];
#pragma unroll
            for (int ct = 0; ct < 4; ++ct) {
                bf16x8_t av = *(const bf16x8_t*)
                    &Vb[(size_t)(ct * 16 + l15) * NPOS + n0 + nc * 32 + g * 8];
                O[ct] = __builtin_amdgcn_mfma_f32_16x16x32_bf16(av, bp.v, O[ct], 0, 0, 0);
            }
        }
    }

    const float inv = 1.f / lsum;
    const float* rb = resid + (size_t)b * CD * NPOS;
    float* ob = outp + (size_t)b * CD * NPOS;
#pragma unroll
    for (int ct = 0; ct < 4; ++ct) {
#pragma unroll
        for (int r = 0; r < 4; ++r) {
            const int c = ct * 16 + g * 4 + r;
            const int m = m0 + l15;
            const size_t idx = (size_t)c * NPOS + m;
            ob[idx] = fmaf(gamma, O[ct][r] * inv, rb[idx]);
        }
    }
}

// ---------------------------------------------------------------------------
extern "C" void kernel_launch(void* const* d_in, const int* in_sizes, int n_in,
                              void* d_out, int out_size, void* d_ws, size_t ws_size,
                              hipStream_t stream)
{
    const float* x    = (const float*)d_in[0];
    const float* y    = (const float*)d_in[1];
    const float* q_w  = (const float*)d_in[2];
    const float* q_s  = (const float*)d_in[3];
    const float* q_b  = (const float*)d_in[4];
    const float* rk_w = (const float*)d_in[5];
    const float* rk_s = (const float*)d_in[6];
    const float* rk_b = (const float*)d_in[7];
    const float* rv_w = (const float*)d_in[8];
    const float* rv_s = (const float*)d_in[9];
    const float* rv_b = (const float*)d_in[10];
    const float* ik_w = (const float*)d_in[11];
    const float* ik_s = (const float*)d_in[12];
    const float* ik_b = (const float*)d_in[13];
    const float* iv_w = (const float*)d_in[14];
    const float* iv_s = (const float*)d_in[15];
    const float* iv_b = (const float*)d_in[16];
    const float* sr_w = (const float*)d_in[17];
    const float* sr_s = (const float*)d_in[18];
    const float* sr_b = (const float*)d_in[19];
    const float* g1   = (const float*)d_in[20];
    const float* g2   = (const float*)d_in[21];

    char* ws = (char*)d_ws;
    const size_t SZ_BF = (size_t)NB * NPOS * CD * 2;   // 2 MB each
    unsigned short* Qt  = (unsigned short*)(ws + 0 * SZ_BF);
    unsigned short* KtR = (unsigned short*)(ws + 1 * SZ_BF);
    unsigned short* KtI = (unsigned short*)(ws + 2 * SZ_BF);
    unsigned short* VR  = (unsigned short*)(ws + 3 * SZ_BF);
    unsigned short* VI  = (unsigned short*)(ws + 4 * SZ_BF);
    float* refR = (float*)(ws + 5 * SZ_BF);
    float* refI = (float*)(ws + 5 * SZ_BF + (size_t)NB * CD * NPOS * 4);

    dim3 cgrid(128, NB);
    // Q = conv(concat(x,y)) -> position-major bf16
    conv3x3_kernel<<<cgrid, 256, 0, stream>>>(x, y, q_w, q_s, q_b, Qt, 128, 0);
    // K/V convs
    conv3x3_kernel<<<cgrid, 256, 0, stream>>>(x, nullptr, rk_w, rk_s, rk_b, KtR, 64, 0);
    conv3x3_kernel<<<cgrid, 256, 0, stream>>>(x, nullptr, rv_w, rv_s, rv_b, VR, 64, 1);
    conv3x3_kernel<<<cgrid, 256, 0, stream>>>(y, nullptr, ik_w, ik_s, ik_b, KtI, 64, 0);
    conv3x3_kernel<<<cgrid, 256, 0, stream>>>(y, nullptr, iv_w, iv_s, iv_b, VI, 64, 1);
    // both attends + residual + gamma -> refine buffers (fp32 NCHW layout)
    attn_kernel<<<dim3(NPOS / 64, NB, 2), 256, 0, stream>>>(
        Qt, KtR, KtI, VR, VI, x, y, g1, g2, refR, refI);
    // final conv(concat(refR, refI)) -> d_out fp32 NCHW
    conv3x3_kernel<<<cgrid, 256, 0, stream>>>(refR, refI, sr_w, sr_s, sr_b,
                                              d_out, 128, 2);
}

// Round 2
// 246.768 us; speedup vs baseline: 3.8719x; 3.8719x over previous
//
#include <hip/hip_runtime.h>
#include <hip/hip_bf16.h>

#define NPOS 4096          // 64*64 positions
#define CD   64            // channels
#define NB   4             // batch
#define PADW 66
#define PADN (66*66)       // padded positions (zero halo)
#define NSEG 4             // attention n-split

typedef __bf16 bf16x8_t __attribute__((ext_vector_type(8)));
typedef float  f32x4_t  __attribute__((ext_vector_type(4)));

static __device__ __forceinline__ unsigned short f2bf(float f) {
    return __builtin_bit_cast(unsigned short, __float2bfloat16(f));
}

static __device__ __forceinline__ void gload_lds16(const void* g, void* l) {
    __builtin_amdgcn_global_load_lds(
        (const __attribute__((address_space(1))) void*)g,
        (__attribute__((address_space(3))) void*)l, 16, 0, 0);
}

// ---------------------------------------------------------------------------
// Pack fp32 NCHW -> bf16 zero-haloed position-major [b][66*66][64].
// grid (64 h, NB, 2 src), block 256. LDS transpose for coalesced r/w.
// Halo stays zero from the hipMemsetAsync in kernel_launch.
// ---------------------------------------------------------------------------
__global__ __launch_bounds__(256) void pack_kernel(
    const float* __restrict__ x, const float* __restrict__ y,
    unsigned short* __restrict__ xpad, unsigned short* __restrict__ ypad)
{
    const int h = blockIdx.x, b = blockIdx.y, src = blockIdx.z;
    const float* in = src ? y : x;
    unsigned short* out = src ? ypad : xpad;
    __shared__ float t[64][65];
    const int tt = threadIdx.x;
    {
        const int ci = tt >> 2, w0 = (tt & 3) * 16;
        const float* p = in + ((size_t)b * 64 + ci) * NPOS + h * 64 + w0;
#pragma unroll
        for (int j = 0; j < 16; j += 4) {
            float4 v = *(const float4*)(p + j);
            t[ci][w0 + j] = v.x; t[ci][w0 + j + 1] = v.y;
            t[ci][w0 + j + 2] = v.z; t[ci][w0 + j + 3] = v.w;
        }
    }
    __syncthreads();
    const int w = tt >> 2, c0 = (tt & 3) * 16;
    unsigned short us[16];
#pragma unroll
    for (int j = 0; j < 16; ++j) us[j] = f2bf(t[c0 + j][w]);
    unsigned short* q = out + ((size_t)b * PADN + (h + 1) * PADW + (w + 1)) * CD + c0;
    *(uint4*)q = *(uint4*)us;
    *(uint4*)(q + 8) = *(uint4*)(us + 8);
}

// ---------------------------------------------------------------------------
// Repack conv weights (OIHW fp32, BN scale folded in) into per-lane MFMA
// B-fragments bf16: Wf[f][cot][lane][8], f = conv-local (src*9+tap)*2+kt.
// conv kt-tap bases: Q=0(36) KR=36(18) VR=54(18) IK=72(18) IV=90(18) SR=108(36)
// grid 144 blocks x 256.
// ---------------------------------------------------------------------------
__global__ __launch_bounds__(256) void wrepack_kernel(
    const float* __restrict__ qw, const float* __restrict__ rkw,
    const float* __restrict__ rvw, const float* __restrict__ ikw,
    const float* __restrict__ ivw, const float* __restrict__ srw,
    const float* __restrict__ qs, const float* __restrict__ rks,
    const float* __restrict__ rvs, const float* __restrict__ iks,
    const float* __restrict__ ivs, const float* __restrict__ srs,
    unsigned short* __restrict__ Wf)
{
    const int f = blockIdx.x;
    const float* w; const float* s; int cin, local;
    if (f < 36)       { w = qw;  s = qs;  cin = 128; local = f; }
    else if (f < 54)  { w = rkw; s = rks; cin = 64;  local = f - 36; }
    else if (f < 72)  { w = rvw; s = rvs; cin = 64;  local = f - 54; }
    else if (f < 90)  { w = ikw; s = iks; cin = 64;  local = f - 72; }
    else if (f < 108) { w = ivw; s = ivs; cin = 64;  local = f - 90; }
    else              { w = srw; s = srs; cin = 128; local = f - 108; }
    const int src = (cin == 128) ? local / 18 : 0;
    const int rem = (cin == 128) ? local % 18 : local;
    const int tap = rem >> 1, kt = rem & 1;
    const int t = threadIdx.x, cot = t >> 6, l = t & 63;
    const int co = cot * 16 + (l & 15);
    const float sc = s[co];
    unsigned short us[8];
#pragma unroll
    for (int e = 0; e < 8; ++e) {
        const int ci = src * 64 + kt * 32 + ((l >> 4) * 8) + e;
        us[e] = f2bf(w[((size_t)co * cin + ci) * 9 + tap] * sc);
    }
    *(uint4*)(Wf + ((size_t)(f * 4 + cot) * 64 + l) * 8) = *(uint4*)us;
}

// ---------------------------------------------------------------------------
// Implicit-GEMM conv3x3 via MFMA. Block = one h row (64 pos) x 64 co,
// 4 waves x 16 pos. A-frag straight from padded bf16 global (L1/L2-hot),
// B-frag from prepacked Wf. D mapping: co = l15, pos = 4g+r.
// grid (64 h, NB, nconv); conv = convid_base + blockIdx.z.
// layouts: 0 = bf16 [n][co], 1 = bf16 [co][n], 2 = fp32 [co][n] (d_out)
// ---------------------------------------------------------------------------
__global__ __launch_bounds__(256) void conv_mfma_kernel(
    const unsigned short* __restrict__ xpad, const unsigned short* __restrict__ ypad,
    const unsigned short* __restrict__ rpadR, const unsigned short* __restrict__ rpadI,
    const unsigned short* __restrict__ Wf,
    const float* __restrict__ qb, const float* __restrict__ rkb,
    const float* __restrict__ rvb, const float* __restrict__ ikb,
    const float* __restrict__ ivb, const float* __restrict__ srb,
    unsigned short* __restrict__ Qt, unsigned short* __restrict__ KtR,
    unsigned short* __restrict__ VR, unsigned short* __restrict__ KtI,
    unsigned short* __restrict__ VI, float* __restrict__ outf,
    int convid_base)
{
    const int conv = convid_base + blockIdx.z;
    const int h = blockIdx.x, b = blockIdx.y;
    const unsigned short *in0, *in1; const float* bias;
    int nsrc, wfbase, layout; void* outp;
    switch (conv) {
        case 0:  in0 = xpad;  in1 = ypad;  nsrc = 2; wfbase = 0;   bias = qb;  outp = Qt;  layout = 0; break;
        case 1:  in0 = xpad;  in1 = 0;     nsrc = 1; wfbase = 36;  bias = rkb; outp = KtR; layout = 0; break;
        case 2:  in0 = xpad;  in1 = 0;     nsrc = 1; wfbase = 54;  bias = rvb; outp = VR;  layout = 1; break;
        case 3:  in0 = ypad;  in1 = 0;     nsrc = 1; wfbase = 72;  bias = ikb; outp = KtI; layout = 0; break;
        case 4:  in0 = ypad;  in1 = 0;     nsrc = 1; wfbase = 90;  bias = ivb; outp = VI;  layout = 1; break;
        default: in0 = rpadR; in1 = rpadI; nsrc = 2; wfbase = 108; bias = srb; outp = outf; layout = 2; break;
    }
    const int lane = threadIdx.x & 63, wv = threadIdx.x >> 6;
    const int l15 = lane & 15, g = lane >> 4;

    f32x4_t acc[4];
#pragma unroll
    for (int i = 0; i < 4; ++i) acc[i] = (f32x4_t){0.f, 0.f, 0.f, 0.f};

    int f = wfbase;
    for (int src = 0; src < nsrc; ++src) {
        const unsigned short* base = (src ? in1 : in0) + (size_t)b * PADN * CD;
        for (int ky = 0; ky < 3; ++ky) {
            for (int kx = 0; kx < 3; ++kx) {
                const int pos = (h + ky) * PADW + wv * 16 + kx + l15;
                const unsigned short* ap = base + (size_t)pos * CD + g * 8;
#pragma unroll
                for (int kt = 0; kt < 2; ++kt, ++f) {
                    bf16x8_t a = *(const bf16x8_t*)(ap + kt * 32);
#pragma unroll
                    for (int cot = 0; cot < 4; ++cot) {
                        bf16x8_t bf = *(const bf16x8_t*)(Wf + ((size_t)(f * 4 + cot) * 64 + lane) * 8);
                        acc[cot] = __builtin_amdgcn_mfma_f32_16x16x32_bf16(a, bf, acc[cot], 0, 0, 0);
                    }
                }
            }
        }
    }

    const int nb4 = h * 64 + wv * 16 + g * 4;   // first of 4 consecutive n
    if (layout == 0) {
        unsigned short* o = (unsigned short*)outp + (size_t)b * NPOS * CD;
#pragma unroll
        for (int cot = 0; cot < 4; ++cot) {
            const int co = cot * 16 + l15;
            const float bv = bias[co];
#pragma unroll
            for (int r = 0; r < 4; ++r)
                o[(size_t)(nb4 + r) * CD + co] = f2bf(fmaxf(acc[cot][r] + bv, 0.f));
        }
    } else if (layout == 1) {
        unsigned short* o = (unsigned short*)outp + (size_t)b * CD * NPOS;
#pragma unroll
        for (int cot = 0; cot < 4; ++cot) {
            const int c = cot * 16 + l15;
            const float bv = bias[c];
            unsigned short us[4];
#pragma unroll
            for (int r = 0; r < 4; ++r) us[r] = f2bf(fmaxf(acc[cot][r] + bv, 0.f));
            *(uint2*)(o + (size_t)c * NPOS + nb4) = *(uint2*)us;
        }
    } else {
        float* o = (float*)outp + (size_t)b * CD * NPOS;
#pragma unroll
        for (int cot = 0; cot < 4; ++cot) {
            const int c = cot * 16 + l15;
            const float bv = bias[c];
            f32x4_t v;
#pragma unroll
            for (int r = 0; r < 4; ++r) v[r] = fmaxf(acc[cot][r] + bv, 0.f);
            *(f32x4_t*)(o + (size_t)c * NPOS + nb4) = v;
        }
    }
}

// ---------------------------------------------------------------------------
// Flash attention over an n-segment; writes unnormalized partials + (m,l).
//   Qt/Kt bf16 [b][n][64]; V bf16 [b][c][n].
// grid (64 mblk, NB, 2att*NSEG), block 256 = 4 waves x 16 m rows.
// Q/V tiles cooperatively staged to LDS via global_load_lds with XOR chunk
// swizzle (store slot = chunk ^ (row&7), applied on the GLOBAL source so the
// LDS dest stays linear; reads apply the same XOR).
// Opart fp32 [att][b][seg][m][c]; ml fp32 [att][b][seg][m][2].
// ---------------------------------------------------------------------------
__global__ __launch_bounds__(256) void attn_kernel(
    const unsigned short* __restrict__ Qt,
    const unsigned short* __restrict__ KtR, const unsigned short* __restrict__ KtI,
    const unsigned short* __restrict__ VR,  const unsigned short* __restrict__ VI,
    float* __restrict__ Opart, float* __restrict__ ml)
{
    const int mblk = blockIdx.x, b = blockIdx.y;
    const int att = blockIdx.z >> 2, seg = blockIdx.z & 3;
    const int lane = threadIdx.x & 63, wv = threadIdx.x >> 6;
    const int l15 = lane & 15, g = lane >> 4;
    const int m0 = mblk * 64 + wv * 16;

    const unsigned short* Qb = Qt + (size_t)b * NPOS * CD;
    const unsigned short* Kb = (att ? KtI : KtR) + (size_t)b * NPOS * CD;
    const unsigned short* Vb = (att ? VI : VR) + (size_t)b * CD * NPOS;

    __shared__ unsigned short Qs[64 * 64];
    __shared__ unsigned short Vs[64 * 64];
    __shared__ unsigned short plds[4][16 * 68];
    unsigned short* pl = plds[wv];

    const bf16x8_t bK0 = *(const bf16x8_t*)&Kb[(size_t)(m0 + l15) * CD + g * 8];
    const bf16x8_t bK1 = *(const bf16x8_t*)&Kb[(size_t)(m0 + l15) * CD + 32 + g * 8];

    f32x4_t O[4];
#pragma unroll
    for (int i = 0; i < 4; ++i) O[i] = (f32x4_t){0.f, 0.f, 0.f, 0.f};
    float mrun = -3.0e38f, lsum = 0.f;

    const int csw = (lane & 7) ^ ((lane >> 3) & 7);   // swizzled source chunk
    const int sx = l15 & 7;                            // read-side XOR key

    for (int it = 0; it < NPOS / NSEG / 64; ++it) {
        const int n0 = seg * (NPOS / NSEG) + it * 64;
        // ---- cooperative stage: Q rows n0..n0+63, V rows c=0..63 ----
#pragma unroll
        for (int j = 0; j < 2; ++j) {
            const int r = wv * 16 + j * 8 + (lane >> 3);
            gload_lds16(Qb + (size_t)(n0 + r) * CD + csw * 8,
                        Qs + (size_t)(wv * 16 + j * 8) * 64);
            gload_lds16(Vb + (size_t)r * NPOS + n0 + csw * 8,
                        Vs + (size_t)(wv * 16 + j * 8) * 64);
        }
        __syncthreads();

        // ---- QK^T (St[row=n_local, col=m]) ----
        f32x4_t St[4];
#pragma unroll
        for (int nt = 0; nt < 4; ++nt) {
            const unsigned short* qr = Qs + (size_t)(nt * 16 + l15) * 64;
            bf16x8_t a0 = *(const bf16x8_t*)(qr + (g ^ sx) * 8);
            bf16x8_t a1 = *(const bf16x8_t*)(qr + ((4 + g) ^ sx) * 8);
            f32x4_t c = (f32x4_t){0.f, 0.f, 0.f, 0.f};
            c = __builtin_amdgcn_mfma_f32_16x16x32_bf16(a0, bK0, c, 0, 0, 0);
            c = __builtin_amdgcn_mfma_f32_16x16x32_bf16(a1, bK1, c, 0, 0, 0);
            St[nt] = c;
        }
        // ---- online softmax (lane's 16 values share m = m0+l15) ----
        float tmax = St[0][0];
#pragma unroll
        for (int nt = 0; nt < 4; ++nt)
#pragma unroll
            for (int r = 0; r < 4; ++r) tmax = fmaxf(tmax, St[nt][r]);
        tmax = fmaxf(tmax, __shfl_xor(tmax, 16));
        tmax = fmaxf(tmax, __shfl_xor(tmax, 32));
        const float mnew = fmaxf(mrun, tmax);
        const float corr = __expf(mrun - mnew);
        float psum = 0.f;
        unsigned int pw[8];
#pragma unroll
        for (int nt = 0; nt < 4; ++nt) {
            float p0 = __expf(St[nt][0] - mnew);
            float p1 = __expf(St[nt][1] - mnew);
            float p2 = __expf(St[nt][2] - mnew);
            float p3 = __expf(St[nt][3] - mnew);
            psum += (p0 + p1) + (p2 + p3);
            pw[nt * 2 + 0] = (unsigned)f2bf(p0) | ((unsigned)f2bf(p1) << 16);
            pw[nt * 2 + 1] = (unsigned)f2bf(p2) | ((unsigned)f2bf(p3) << 16);
        }
        psum += __shfl_xor(psum, 16);
        psum += __shfl_xor(psum, 32);
        lsum = lsum * corr + psum;
        mrun = mnew;
#pragma unroll
        for (int i = 0; i < 4; ++i) {
            O[i][0] *= corr; O[i][1] *= corr; O[i][2] *= corr; O[i][3] *= corr;
        }
        // ---- P -> per-wave LDS ----
#pragma unroll
        for (int nt = 0; nt < 4; ++nt)
            *(uint2*)&pl[l15 * 68 + nt * 16 + g * 4] =
                make_uint2(pw[nt * 2], pw[nt * 2 + 1]);
        // ---- PV: O[c,m] += V[c,:] P[m,:] ----
#pragma unroll
        for (int nc = 0; nc < 2; ++nc) {
            union { bf16x8_t v; uint2 d2[2]; } bp;
            bp.d2[0] = *(uint2*)&pl[l15 * 68 + nc * 32 + g * 8];
            bp.d2[1] = *(uint2*)&pl[l15 * 68 + nc * 32 + g * 8 + 4];
#pragma unroll
            for (int ct = 0; ct < 4; ++ct) {
                bf16x8_t av = *(const bf16x8_t*)
                    (Vs + (size_t)(ct * 16 + l15) * 64 + (((nc * 4 + g) ^ sx) * 8));
                O[ct] = __builtin_amdgcn_mfma_f32_16x16x32_bf16(av, bp.v, O[ct], 0, 0, 0);
            }
        }
        __syncthreads();   // all reads done before next stage
    }

    // ---- write partials [att][b][seg][m][c] ----
    float* Ob = Opart + ((((size_t)att * NB + b) * NSEG + seg) * NPOS) * CD;
    const int m = m0 + l15;
#pragma unroll
    for (int ct = 0; ct < 4; ++ct)
        *(f32x4_t*)(Ob + (size_t)m * CD + ct * 16 + g * 4) = O[ct];
    if (g == 0) {
        float* mlb = ml + ((((size_t)att * NB + b) * NSEG + seg) * NPOS + m) * 2;
        mlb[0] = mrun; mlb[1] = lsum;
    }
}

// ---------------------------------------------------------------------------
// Combine NSEG partials -> refine = gamma*O/L + resid, written bf16 into the
// zero-haloed padded layout for the SR conv. grid (64 mtile, NB, 2 att).
// ---------------------------------------------------------------------------
__global__ __launch_bounds__(256) void combine_kernel(
    const float* __restrict__ Opart, const float* __restrict__ ml,
    const float* __restrict__ x, const float* __restrict__ y,
    const float* __restrict__ g1, const float* __restrict__ g2,
    unsigned short* __restrict__ rpadR, unsigned short* __restrict__ rpadI)
{
    const int mt = blockIdx.x, b = blockIdx.y, att = blockIdx.z;
    const float* resid = att ? x : y;
    const float gamma = att ? g2[0] : g1[0];
    unsigned short* rp = (att ? rpadI : rpadR) + (size_t)b * PADN * CD;
    __shared__ float t[64][65];
    const int tt = threadIdx.x;
    {
        const int c = tt >> 2, w0 = (tt & 3) * 16;
        const float* p = resid + ((size_t)b * CD + c) * NPOS + mt * 64 + w0;
#pragma unroll
        for (int j = 0; j < 16; j += 4) {
            float4 v = *(const float4*)(p + j);
            t[c][w0 + j] = v.x; t[c][w0 + j + 1] = v.y;
            t[c][w0 + j + 2] = v.z; t[c][w0 + j + 3] = v.w;
        }
    }
    __syncthreads();
    const int c = tt & 63, mq = tt >> 6;
    const size_t ob = (((size_t)att * NB + b) * NSEG) * NPOS * CD;
    const size_t mb = (((size_t)att * NB + b) * NSEG) * NPOS;
    for (int p = 0; p < 16; ++p) {
        const int mloc = mq * 16 + p;
        const int m = mt * 64 + mloc;
        float mm[NSEG], llv[NSEG];
#pragma unroll
        for (int s = 0; s < NSEG; ++s) {
            mm[s] = ml[(mb + (size_t)s * NPOS + m) * 2];
            llv[s] = ml[(mb + (size_t)s * NPOS + m) * 2 + 1];
        }
        float M = mm[0];
#pragma unroll
        for (int s = 1; s < NSEG; ++s) M = fmaxf(M, mm[s]);
        float Ov = 0.f, L = 0.f;
#pragma unroll
        for (int s = 0; s < NSEG; ++s) {
            const float wgt = __expf(mm[s] - M);
            L += wgt * llv[s];
            Ov += wgt * Opart[ob + ((size_t)s * NPOS + m) * CD + c];
        }
        const float val = fmaf(gamma, Ov / L, t[c][mloc]);
        const int h = m >> 6, w_ = m & 63;
        rp[((size_t)((h + 1) * PADW) + (w_ + 1)) * CD + c] = f2bf(val);
    }
}

// ---------------------------------------------------------------------------
extern "C" void kernel_launch(void* const* d_in, const int* in_sizes, int n_in,
                              void* d_out, int out_size, void* d_ws, size_t ws_size,
                              hipStream_t stream)
{
    const float* x    = (const float*)d_in[0];
    const float* y    = (const float*)d_in[1];
    const float* q_w  = (const float*)d_in[2];
    const float* q_s  = (const float*)d_in[3];
    const float* q_b  = (const float*)d_in[4];
    const float* rk_w = (const float*)d_in[5];
    const float* rk_s = (const float*)d_in[6];
    const float* rk_b = (const float*)d_in[7];
    const float* rv_w = (const float*)d_in[8];
    const float* rv_s = (const float*)d_in[9];
    const float* rv_b = (const float*)d_in[10];
    const float* ik_w = (const float*)d_in[11];
    const float* ik_s = (const float*)d_in[12];
    const float* ik_b = (const float*)d_in[13];
    const float* iv_w = (const float*)d_in[14];
    const float* iv_s = (const float*)d_in[15];
    const float* iv_b = (const float*)d_in[16];
    const float* sr_w = (const float*)d_in[17];
    const float* sr_s = (const float*)d_in[18];
    const float* sr_b = (const float*)d_in[19];
    const float* g1   = (const float*)d_in[20];
    const float* g2   = (const float*)d_in[21];

    char* ws = (char*)d_ws;
    size_t off = 0;
    auto alloc = [&](size_t bytes) {
        void* p = ws + off; off += (bytes + 255) & ~(size_t)255; return p;
    };
    const size_t PADB = (size_t)NB * PADN * CD * 2;
    unsigned short* xpad  = (unsigned short*)alloc(PADB);
    unsigned short* ypad  = (unsigned short*)alloc(PADB);
    unsigned short* rpadR = (unsigned short*)alloc(PADB);
    unsigned short* rpadI = (unsigned short*)alloc(PADB);
    const size_t padTotal = off;                       // 4 pads contiguous
    unsigned short* Qt  = (unsigned short*)alloc((size_t)NB * NPOS * CD * 2);
    unsigned short* KtR = (unsigned short*)alloc((size_t)NB * NPOS * CD * 2);
    unsigned short* KtI = (unsigned short*)alloc((size_t)NB * NPOS * CD * 2);
    unsigned short* VR  = (unsigned short*)alloc((size_t)NB * NPOS * CD * 2);
    unsigned short* VI  = (unsigned short*)alloc((size_t)NB * NPOS * CD * 2);
    unsigned short* Wf  = (unsigned short*)alloc((size_t)144 * 4 * 64 * 16);
    float* Opart = (float*)alloc((size_t)2 * NB * NSEG * NPOS * CD * 4);
    float* mlb   = (float*)alloc((size_t)2 * NB * NSEG * NPOS * 2 * 4);

    // zero halos of all 4 padded buffers (contiguous region)
    hipMemsetAsync(ws, 0, padTotal, stream);

    wrepack_kernel<<<dim3(144), 256, 0, stream>>>(
        q_w, rk_w, rv_w, ik_w, iv_w, sr_w,
        q_s, rk_s, rv_s, ik_s, iv_s, sr_s, Wf);
    pack_kernel<<<dim3(64, NB, 2), 256, 0, stream>>>(x, y, xpad, ypad);
    // 5 pre-attention convs in one launch
    conv_mfma_kernel<<<dim3(64, NB, 5), 256, 0, stream>>>(
        xpad, ypad, rpadR, rpadI, Wf,
        q_b, rk_b, rv_b, ik_b, iv_b, sr_b,
        Qt, KtR, VR, KtI, VI, nullptr, 0);
    attn_kernel<<<dim3(64, NB, 2 * NSEG), 256, 0, stream>>>(
        Qt, KtR, KtI, VR, VI, Opart, mlb);
    combine_kernel<<<dim3(64, NB, 2), 256, 0, stream>>>(
        Opart, mlb, x, y, g1, g2, rpadR, rpadI);
    // final SR conv -> d_out fp32 NCHW
    conv_mfma_kernel<<<dim3(64, NB, 1), 256, 0, stream>>>(
        xpad, ypad, rpadR, rpadI, Wf,
        q_b, rk_b, rv_b, ik_b, iv_b, sr_b,
        Qt, KtR, VR, KtI, VI, (float*)d_out, 5);
}